// Round 22
// baseline (132.914 us; speedup 1.0000x reference)
//
#include <hip/hip_runtime.h>
#include <math.h>

#define BB 64
#define LL 256
#define DD 1024
#define NDPAD 512   // padded anti-diagonal count per batch (511 real + 1 pad)
#define BK 32
#define LOG2E 1.4426950408889634f
#define LN2   0.6931471805599453f

typedef __attribute__((ext_vector_type(8))) short short8v;
typedef __attribute__((ext_vector_type(4))) float float4v;

__device__ __forceinline__ unsigned short f2bf(float f) {
    unsigned u = __float_as_uint(f);
    unsigned r = (u + 0x7fffu + ((u >> 16) & 1u)) >> 16;   // RNE
    return (unsigned short)r;
}
__device__ __forceinline__ float bf2f(unsigned short u) {
    return __uint_as_float(((unsigned)u) << 16);
}
// packed RNE convert: dst = (bf16(hi)<<16) | bf16(lo)
__device__ __forceinline__ unsigned cvtpk(float lo, float hi) {
    unsigned r;
    asm("v_cvt_pk_bf16_f32 %0, %1, %2" : "=v"(r) : "v"(lo), "v"(hi));
    return r;
}
// lane i <- lane i-1 via DPP wave_shr:1; lane 0 <- fill
__device__ __forceinline__ float wshr1(float src, float fill) {
    return __int_as_float(__builtin_amdgcn_update_dpp(
        __float_as_int(fill), __float_as_int(src), 0x138, 0xF, 0xF, false));
}

// ================= MEGA: fused dist tile + (tile0 blocks) soft-DTW DP =================
// Fused part = R16 structure exactly (best measured): 128x128 tile, in-block
// K-split (waves 0-3 k<512, waves 4-7 k>=512), conflict-free swizzle s^((r>>1)&3),
// lgkm-only phase barriers. After the tile: release flags[4b+tile]. Blocks with
// tile==0 continue into the verified 4-wave chunk-skewed sdtw for batch b,
// gating chunk>=8 prefetch on tiles 1,2 and chunk>=16 on tile 3 (same-XCD flags).
__global__ __launch_bounds__(512) void mega_kernel(const float* __restrict__ S,
                                                   const float* __restrict__ T,
                                                   unsigned short* __restrict__ Dd,
                                                   int* __restrict__ flags,
                                                   float* __restrict__ res) {
    __shared__ __align__(16) unsigned char smem[67968];
    // fused views
    auto LDSU = [&](int p, int buf, int ab) -> unsigned short* {
        return (unsigned short*)smem + ((p * 4 + buf * 2 + ab) * 128 * BK);
    };
    float* nrmB = (float*)(smem + 65536);            // [2][2][128] = 2048 B

    const int bid  = blockIdx.x;
    const int b    = bid & 63;
    const int tile = bid >> 6;
    const int i0 = (tile & 1) * 128;
    const int j0 = (tile >> 1) * 128;
    const int tid = threadIdx.x, w = tid >> 6, lane = tid & 63;
    const int p = w >> 2;                    // K-pipeline (0: k<512, 1: k>=512)
    const int q = w & 3;                     // role within pipeline
    const int wr = q >> 1, wc = q & 1;
    const int kbase = p * 512;

    const float* Sg = S + ((size_t)b * LL + i0) * DD;
    const float* Tg = T + ((size_t)b * LL + j0) * DD;

    const int sr   = q * 16 + (lane >> 2);   // staging row within 64-row half
    const int slot = lane & 3;               // lds PHYS k-slot this lane fills
    const int kb   = slot ^ ((sr >> 1) & 3); // GLOBAL k-slot (conflict-free swizzle)

    float4v acc[4][4];
    const float4v fzero = {0.f, 0.f, 0.f, 0.f};
    #pragma unroll
    for (int mi = 0; mi < 4; ++mi)
        #pragma unroll
        for (int ni = 0; ni < 4; ++ni) acc[mi][ni] = fzero;

    struct Stg { float4 a[2][2]; float4 bb[2][2]; };
    Stg st0, st1;
    float ns[2][2] = {};

    auto issue = [&](Stg& s, int kt) {
        const float* pa = Sg + (size_t)sr * DD + kbase + kt * BK + kb * 8;
        const float* pb = Tg + (size_t)sr * DD + kbase + kt * BK + kb * 8;
        s.a[0][0]  = *(const float4*)(pa);
        s.a[0][1]  = *(const float4*)(pa + 4);
        s.a[1][0]  = *(const float4*)(pa + 64 * DD);
        s.a[1][1]  = *(const float4*)(pa + 64 * DD + 4);
        s.bb[0][0] = *(const float4*)(pb);
        s.bb[0][1] = *(const float4*)(pb + 4);
        s.bb[1][0] = *(const float4*)(pb + 64 * DD);
        s.bb[1][1] = *(const float4*)(pb + 64 * DD + 4);
    };

    auto cvtwrite = [&](const float4& v0, const float4& v1, unsigned short* dst, float& nacc) {
        nacc += v0.x * v0.x + v0.y * v0.y + v0.z * v0.z + v0.w * v0.w
              + v1.x * v1.x + v1.y * v1.y + v1.z * v1.z + v1.w * v1.w;
        uint4 o;
        o.x = cvtpk(v0.x, v0.y);
        o.y = cvtpk(v0.z, v0.w);
        o.z = cvtpk(v1.x, v1.y);
        o.w = cvtpk(v1.z, v1.w);
        *(uint4*)dst = o;
    };

    auto commit = [&](Stg& s, int buf) {
        #pragma unroll
        for (int n = 0; n < 2; ++n) {
            cvtwrite(s.a[n][0],  s.a[n][1],  LDSU(p, buf, 0) + (n * 64 + sr) * BK + slot * 8, ns[0][n]);
            cvtwrite(s.bb[n][0], s.bb[n][1], LDSU(p, buf, 1) + (n * 64 + sr) * BK + slot * 8, ns[1][n]);
        }
    };

    auto compute = [&](int buf) {
        const unsigned short* LA = LDSU(p, buf, 0);
        const unsigned short* LB = LDSU(p, buf, 1);
        short8v af[4], bf[4];
        #pragma unroll
        for (int mi = 0; mi < 4; ++mi) {
            int row = wr * 64 + mi * 16 + (lane & 15);
            int kbf = (lane >> 4) ^ ((row >> 1) & 3);
            af[mi] = *(const short8v*)(LA + row * BK + kbf * 8);
        }
        #pragma unroll
        for (int ni = 0; ni < 4; ++ni) {
            int row = wc * 64 + ni * 16 + (lane & 15);
            int kbf = (lane >> 4) ^ ((row >> 1) & 3);
            bf[ni] = *(const short8v*)(LB + row * BK + kbf * 8);
        }
        #pragma unroll
        for (int mi = 0; mi < 4; ++mi)
            #pragma unroll
            for (int ni = 0; ni < 4; ++ni)
                acc[mi][ni] = __builtin_amdgcn_mfma_f32_16x16x32_bf16(af[mi], bf[ni],
                                                                      acc[mi][ni], 0, 0, 0);
    };

    auto phase_barrier = [&]() {
        asm volatile("s_waitcnt lgkmcnt(0)" ::: "memory");
        __builtin_amdgcn_s_barrier();
        __builtin_amdgcn_sched_barrier(0);
    };

    issue(st0, 0);
    for (int kt2 = 0; kt2 < 16; kt2 += 2) {
        issue(st1, kt2 + 1);
        commit(st0, 0);
        phase_barrier();
        compute(0);
        if (kt2 + 2 < 16) issue(st0, kt2 + 2);
        commit(st1, 1);
        phase_barrier();
        compute(1);
    }

    #pragma unroll
    for (int side = 0; side < 2; ++side)
        #pragma unroll
        for (int n = 0; n < 2; ++n) {
            float s = ns[side][n];
            s += __shfl_xor(s, 1, 64);
            s += __shfl_xor(s, 2, 64);
            if (slot == 0) nrmB[(p * 2 + side) * 128 + n * 64 + sr] = s;
        }
    __syncthreads();

    float* cb = (float*)smem;
    if (p == 1) {
        #pragma unroll
        for (int mi = 0; mi < 4; ++mi)
            #pragma unroll
            for (int ni = 0; ni < 4; ++ni)
                *(float4v*)(cb + q * 4096 + (mi * 4 + ni) * 256 + lane * 4) = acc[mi][ni];
    }
    __syncthreads();

    if (p == 0) {
        #pragma unroll
        for (int mi = 0; mi < 4; ++mi)
            #pragma unroll
            for (int ni = 0; ni < 4; ++ni)
                acc[mi][ni] += *(const float4v*)(cb + q * 4096 + (mi * 4 + ni) * 256 + lane * 4);

        const int r0 = (lane >> 4) * 4;
        const int cf = lane & 15;
        unsigned short* Db = Dd + (size_t)b * NDPAD * 256;
        #pragma unroll
        for (int mi = 0; mi < 4; ++mi) {
            #pragma unroll
            for (int ni = 0; ni < 4; ++ni) {
                int lj = wc * 64 + ni * 16 + cf;
                float tj = nrmB[1 * 128 + lj] + nrmB[3 * 128 + lj];
                int j = j0 + lj;
                #pragma unroll
                for (int rg = 0; rg < 4; ++rg) {
                    int li = wr * 64 + mi * 16 + r0 + rg;
                    float sq = nrmB[0 * 128 + li] + nrmB[2 * 128 + li] + tj - 2.0f * acc[mi][ni][rg];
                    float dv = sqrtf(fmaxf(sq, 1e-12f));
                    int i = i0 + li;
                    Db[(size_t)(i + j) * 256 + j] = f2bf(dv * LOG2E);
                }
            }
        }
    }

    // ---- release: all stores done -> set this tile's flag (device-scope) ----
    __threadfence();                       // drain own stores (vmcnt0 + cache ops)
    __syncthreads();                       // all threads' stores drained
    if (tid == 0) atomicAdd(&flags[4 * b + tile], 1);

    if (tile != 0) return;

    // ================= sdtw phase (tile0 blocks only, batch b) =================
    __syncthreads();                       // LDS (cb/nrm) free for reuse
    unsigned short* sdb = (unsigned short*)smem;        // 8 chunks x 4096 ushorts
    float* bbuf = (float*)(smem + 65536);               // [3][2][16] = 384 B
    const unsigned short* Db = Dd + (size_t)b * NDPAD * 256;
    const float INF = INFINITY;

    auto prefetch = [&](int c) {
        #pragma unroll
        for (int qq = 0; qq < 8; ++qq) {
            __builtin_amdgcn_global_load_lds(
                (const __attribute__((address_space(1))) void*)(Db + (size_t)c * 4096 + qq * 512 + lane * 8),
                (__attribute__((address_space(3))) void*)(sdb + (c & 7) * 4096 + qq * 512),
                16, 0, 0);
        }
    };
    auto waitflag = [&](int idx) {
        if (lane == 0) {
            while (atomicAdd(&flags[idx], 0) == 0) __builtin_amdgcn_s_sleep(16);
        }
        __threadfence();                   // acquire: invalidate L1 before reads
    };

    const int cw   = (w < 4) ? w : 64;     // waves 4-7: never in compute range
    const int col0 = 64 * (w & 3) + lane;
    float rm1 = INF, rm2 = INF;
    float p2carry = (tid == 0) ? 0.0f : INF;
    float bcarry = INF;

    if (w == 0) {
        prefetch(0);                       // chunks 0,1: d<=47, own tile only
        prefetch(1);
        asm volatile("s_waitcnt vmcnt(8)" ::: "memory");
    }
    asm volatile("s_waitcnt lgkmcnt(0)" ::: "memory");
    __builtin_amdgcn_s_barrier();

    for (int r = 0; r < 35; ++r) {
        if (w == 0 && r + 2 < 32) {
            if (r + 2 == 8)  { waitflag(4 * b + 1); waitflag(4 * b + 2); }
            if (r + 2 == 16) { waitflag(4 * b + 3); }
            prefetch(r + 2);
        }
        const int c = r - cw;
        if (0 <= c && c < 32) {
            const unsigned short* Lp = sdb + (c & 7) * 4096;
            float dv[16];
            #pragma unroll
            for (int qq = 0; qq < 16; ++qq)
                dv[qq] = bf2f(Lp[qq * 256 + col0]);

            float bv[16];
            if (w == 0) {
                #pragma unroll
                for (int qq = 0; qq < 16; ++qq) bv[qq] = INF;
            } else {
                const float4* bp4 = (const float4*)(bbuf + ((w - 1) * 2 + (c & 1)) * 16);
                float4 b0 = bp4[0], b1 = bp4[1], b2 = bp4[2], b3 = bp4[3];
                bv[0] = bcarry;
                bv[1] = b0.x;  bv[2] = b0.y;  bv[3] = b0.z;  bv[4] = b0.w;
                bv[5] = b1.x;  bv[6] = b1.y;  bv[7] = b1.z;  bv[8] = b1.w;
                bv[9] = b2.x;  bv[10] = b2.y; bv[11] = b2.z; bv[12] = b2.w;
                bv[13] = b3.x; bv[14] = b3.y; bv[15] = b3.z;
                bcarry = b3.w;
            }
            asm volatile("s_waitcnt lgkmcnt(0)" ::: "memory");
            __builtin_amdgcn_sched_barrier(0);

            const int ibase = 16 * c - col0;
            float bb[16];
            #pragma unroll
            for (int qq = 0; qq < 16; ++qq) {
                float p1 = wshr1(rm1, bv[qq]);
                float p2 = p2carry;
                p2carry = p1;
                float m   = fminf(p2, fminf(rm1, p1));
                float mid = __builtin_amdgcn_fmed3f(p2, rm1, p1);
                float M   = fmaxf(p2, fmaxf(rm1, p1));
                float s   = (__builtin_amdgcn_exp2f(m - mid) +
                             __builtin_amdgcn_exp2f(m - M)) + 1.0f;
                float rcv = dv[qq] + m - __builtin_amdgcn_logf(s);
                bool valid = (unsigned)(ibase + qq) < 256u;
                rcv = valid ? rcv : INF;
                rm2 = rm1;
                rm1 = rcv;
                bb[qq] = rcv;
            }
            if (w < 3 && lane == 63) {
                float4* op = (float4*)(bbuf + (w * 2 + (c & 1)) * 16);
                op[0] = make_float4(bb[0], bb[1], bb[2], bb[3]);
                op[1] = make_float4(bb[4], bb[5], bb[6], bb[7]);
                op[2] = make_float4(bb[8], bb[9], bb[10], bb[11]);
                op[3] = make_float4(bb[12], bb[13], bb[14], bb[15]);
            }
        }
        if (w == 0) {
            // FIFO vmcnt: chunk r complete <=> <=16 outstanding (r+1, r+2 in flight)
            if (r < 30)       asm volatile("s_waitcnt vmcnt(16)" ::: "memory");
            else if (r == 30) asm volatile("s_waitcnt vmcnt(8)" ::: "memory");
            else if (r == 31) asm volatile("s_waitcnt vmcnt(0)" ::: "memory");
        }
        asm volatile("s_waitcnt lgkmcnt(0)" ::: "memory");
        __builtin_amdgcn_s_barrier();
    }
    if (tid == 255) res[b] = rm2 * LN2;
}

// ---------- final mean over batches ----------
__global__ void reduce_kernel(const float* __restrict__ res, float* __restrict__ out) {
    int t = threadIdx.x;
    float v = res[t];
    #pragma unroll
    for (int off = 32; off; off >>= 1) v += __shfl_down(v, off, 64);
    if (t == 0) out[0] = v * (1.0f / BB);
}

extern "C" void kernel_launch(void* const* d_in, const int* in_sizes, int n_in,
                              void* d_out, int out_size, void* d_ws, size_t ws_size,
                              hipStream_t stream) {
    const float* S = (const float*)d_in[0];
    const float* T = (const float*)d_in[1];

    const size_t nDiag = (size_t)BB * NDPAD * 256;   // 8,388,608 ushorts (16.8 MB)
    unsigned short* diag = (unsigned short*)d_ws;
    float* rsv  = (float*)(diag + nDiag);
    int*   flags = (int*)(rsv + 64);                 // 256 ints

    hipMemsetAsync(flags, 0, 256 * sizeof(int), stream);
    mega_kernel<<<4 * BB, 512, 0, stream>>>(S, T, diag, flags, rsv);
    reduce_kernel<<<1, 64, 0, stream>>>(rsv, (float*)d_out);
}